// Round 17
// baseline (942.810 us; speedup 1.0000x reference)
//
#include <hip/hip_runtime.h>
#include <hip/hip_cooperative_groups.h>
#include <hip/hip_bf16.h>
#include <hip/hip_fp16.h>
#include <math.h>

namespace cg = cooperative_groups;

// ---------------------------------------------------------------------------
// DisplacementTensors.  R27: ONE cooperative kernel (6 phases, grid.sync
// between) -- R16 decomposition showed ~75 us of inter-dispatch dead time
// (~10-12 us per graph node) on top of ~70 us of actual work.  Phases:
//   1 wcat f32 concat + zero counts      (grid-stride)
//   2 rank atomics + table build         (grid-stride; table keeps its
//                                         intra-block LDS pipeline)
//   3a coarse sums  3b rowstart prefix   (wave per 64-node group)
//   4 payload place                      (grid-stride)
//   5 nodes: R25 asm counted-vmcnt pipeline (proven, 191.8 us config)
// Runtime fallback: if hipLaunchCooperativeKernel errors, run the R26
// 6-kernel chain (kept verbatim below; best measured 191.8 us).
// Ledger: NT stores = 3x write amp (R12); source ILP defeated by scheduler
// (R14-16); asm batches only reliable tool (R17); bf16 per-FMA weight reads
// = 10x table regression (R22); 1-block scan = ~25 us (R23); all-parallel
// grids + fewer dispatches = 201->191.8 (R26).
// ---------------------------------------------------------------------------

#define TSIZE 8192
#define DMAX  2.0f
#define EPB   4              // table entries per block (4 waves)
#define NPB   4              // waves per block in nodes phase
#define ROWB  512            // table row bytes (32 ch x 16 B)
#define ROWF  128            // table row floats

#define O_WRAD 0
#define O_BRAD 256
#define O_WDIR 288
#define O_W1   1312
#define O_B1   3360
#define O_W2   3424
#define O_B2   7520
#define O_W3   7584
#define O_B3   9632
#define O_WV   9664
#define O_WD   10688
#define W_TOT  11712

typedef float        f32x4 __attribute__((ext_vector_type(4)));
typedef unsigned int u32x2 __attribute__((ext_vector_type(2)));

struct TE { float r, v, d; };

__device__ __forceinline__ float lrelu(float x) { return x > 0.0f ? x : 0.1f * x; }

__device__ __forceinline__ float ldf(const void* p, int i, bool f32) {
    return f32 ? ((const float*)p)[i]
               : __uint_as_float(((unsigned int)((const unsigned short*)p)[i]) << 16);
}
__device__ __forceinline__ void stf(void* p, size_t i, float v, bool f32) {
    if (f32) ((float*)p)[i] = v;
    else     ((__hip_bfloat16*)p)[i] = __float2bfloat16(v);
}

__device__ __forceinline__ bool detect_f32(const void* r) {
    const unsigned short* p = (const unsigned short*)r;
    int bad = 0;
#pragma unroll 8
    for (int i = 0; i < 128; i++) {
        float v = __uint_as_float(((unsigned int)p[i]) << 16);
        bad |= (!isfinite(v) || fabsf(v) > 1e5f) ? 1 : 0;
    }
    return bad != 0;
}

// ---- asm load batches (R17/R25, proven) -----------------------------------
__device__ __forceinline__ void load8x16(
    const void* p0, const void* p1, const void* p2, const void* p3,
    const void* p4, const void* p5, const void* p6, const void* p7,
    f32x4& q0, f32x4& q1, f32x4& q2, f32x4& q3,
    f32x4& q4, f32x4& q5, f32x4& q6, f32x4& q7) {
    asm volatile(
        "global_load_dwordx4 %0, %8, off\n\t"
        "global_load_dwordx4 %1, %9, off\n\t"
        "global_load_dwordx4 %2, %10, off\n\t"
        "global_load_dwordx4 %3, %11, off\n\t"
        "global_load_dwordx4 %4, %12, off\n\t"
        "global_load_dwordx4 %5, %13, off\n\t"
        "global_load_dwordx4 %6, %14, off\n\t"
        "global_load_dwordx4 %7, %15, off\n\t"
        "s_waitcnt vmcnt(0)"
        : "=&v"(q0), "=&v"(q1), "=&v"(q2), "=&v"(q3),
          "=&v"(q4), "=&v"(q5), "=&v"(q6), "=&v"(q7)
        : "v"(p0), "v"(p1), "v"(p2), "v"(p3),
          "v"(p4), "v"(p5), "v"(p6), "v"(p7));
}
__device__ __forceinline__ void load8x16_nw(
    const void* p0, const void* p1, const void* p2, const void* p3,
    const void* p4, const void* p5, const void* p6, const void* p7,
    f32x4& q0, f32x4& q1, f32x4& q2, f32x4& q3,
    f32x4& q4, f32x4& q5, f32x4& q6, f32x4& q7) {
    asm volatile(
        "global_load_dwordx4 %0, %8, off\n\t"
        "global_load_dwordx4 %1, %9, off\n\t"
        "global_load_dwordx4 %2, %10, off\n\t"
        "global_load_dwordx4 %3, %11, off\n\t"
        "global_load_dwordx4 %4, %12, off\n\t"
        "global_load_dwordx4 %5, %13, off\n\t"
        "global_load_dwordx4 %6, %14, off\n\t"
        "global_load_dwordx4 %7, %15, off"
        : "=&v"(q0), "=&v"(q1), "=&v"(q2), "=&v"(q3),
          "=&v"(q4), "=&v"(q5), "=&v"(q6), "=&v"(q7)
        : "v"(p0), "v"(p1), "v"(p2), "v"(p3),
          "v"(p4), "v"(p5), "v"(p6), "v"(p7));
}
__device__ __forceinline__ void waitv8(
    f32x4& r0, f32x4& r1, f32x4& r2, f32x4& r3,
    f32x4& r4, f32x4& r5, f32x4& r6, f32x4& r7) {
    asm volatile("s_waitcnt vmcnt(8)"
        : "+v"(r0), "+v"(r1), "+v"(r2), "+v"(r3),
          "+v"(r4), "+v"(r5), "+v"(r6), "+v"(r7));
}
__device__ __forceinline__ void waitv0(
    f32x4& r0, f32x4& r1, f32x4& r2, f32x4& r3,
    f32x4& r4, f32x4& r5, f32x4& r6, f32x4& r7) {
    asm volatile("s_waitcnt vmcnt(0)"
        : "+v"(r0), "+v"(r1), "+v"(r2), "+v"(r3),
          "+v"(r4), "+v"(r5), "+v"(r6), "+v"(r7));
}

#define ACC16(Q, U)                                                           \
    do {                                                                      \
        const float x = (Q).x, y = (Q).y, z = (Q).z;                          \
        accA += (U).x;                                                        \
        v0 += (U).y * x; v1 += (U).y * y; v2 += (U).y * z;                    \
        const float _tx = (U).z * x, _ty = (U).z * y, _tz = (U).z * z;        \
        d00 += _tx * x; d01 += _tx * y; d02 += _tx * z;                       \
        d10 += _ty * x; d11 += _ty * y; d12 += _ty * z;                       \
        d20 += _tz * x; d21 += _tz * y; d22 += _tz * z;                       \
    } while (0)

#define P8ARGS(R) R##0, R##1, R##2, R##3, R##4, R##5, R##6, R##7
#define LOADP_NW(R, IDX)                                                      \
    do { const char* _pp = (const char*)epsv + (size_t)(IDX) * 16;            \
         load8x16_nw(_pp, _pp + 16, _pp + 32, _pp + 48,                       \
                     _pp + 64, _pp + 80, _pp + 96, _pp + 112, P8ARGS(R));     \
    } while (0)
#define LOADT_NW(R, Q)                                                        \
    load8x16_nw(tabA + __float_as_int((Q##0).w),                              \
                tabA + __float_as_int((Q##1).w),                              \
                tabA + __float_as_int((Q##2).w),                              \
                tabA + __float_as_int((Q##3).w),                              \
                tabA + __float_as_int((Q##4).w),                              \
                tabA + __float_as_int((Q##5).w),                              \
                tabA + __float_as_int((Q##6).w),                              \
                tabA + __float_as_int((Q##7).w),                              \
                P8ARGS(R))
#define ACCB(Q, T)                                                            \
    do { ACC16(Q##0, T##0); ACC16(Q##1, T##1); ACC16(Q##2, T##2);             \
         ACC16(Q##3, T##3); ACC16(Q##4, T##4); ACC16(Q##5, T##5);             \
         ACC16(Q##6, T##6); ACC16(Q##7, T##7); } while (0)

// edge-accumulation body shared by fused phase 5 and fallback k_nodes2
#define NODES_BODY_P16()                                                      \
    do {                                                                      \
        int i = 0;                                                            \
        if (minl >= 8) {                                                      \
            f32x4 pa0, pa1, pa2, pa3, pa4, pa5, pa6, pa7;                     \
            f32x4 pb0, pb1, pb2, pb3, pb4, pb5, pb6, pb7;                     \
            f32x4 tt0, tt1, tt2, tt3, tt4, tt5, tt6, tt7;                     \
            LOADP_NW(pa, s0);                                                 \
            waitv0(P8ARGS(pa));                                               \
            for (; i + 24 <= minl; i += 16) {                                 \
                LOADT_NW(tt, pa);                                             \
                LOADP_NW(pb, s0 + i + 8);                                     \
                waitv8(P8ARGS(tt));                                           \
                ACCB(pa, tt);                                                 \
                waitv0(P8ARGS(pb));                                           \
                LOADT_NW(tt, pb);                                             \
                LOADP_NW(pa, s0 + i + 16);                                    \
                waitv8(P8ARGS(tt));                                           \
                ACCB(pb, tt);                                                 \
                waitv0(P8ARGS(pa));                                           \
            }                                                                 \
            if (i + 16 <= minl) {                                             \
                LOADT_NW(tt, pa);                                             \
                LOADP_NW(pb, s0 + i + 8);                                     \
                waitv8(P8ARGS(tt));                                           \
                ACCB(pa, tt);                                                 \
                waitv0(P8ARGS(pb));                                           \
                LOADT_NW(tt, pb);                                             \
                waitv0(P8ARGS(tt));                                           \
                ACCB(pb, tt);                                                 \
                i += 16;                                                      \
            } else {                                                          \
                LOADT_NW(tt, pa);                                             \
                waitv0(P8ARGS(tt));                                           \
                ACCB(pa, tt);                                                 \
                i += 8;                                                       \
            }                                                                 \
        }                                                                     \
        for (; i < maxl; i += 8) {                                            \
            float m0, m1, m2, m3, m4, m5, m6, m7;                             \
            m0 = (i + 0 < mylen) ? 1.f : 0.f;                                 \
            m1 = (i + 1 < mylen) ? 1.f : 0.f;                                 \
            m2 = (i + 2 < mylen) ? 1.f : 0.f;                                 \
            m3 = (i + 3 < mylen) ? 1.f : 0.f;                                 \
            m4 = (i + 4 < mylen) ? 1.f : 0.f;                                 \
            m5 = (i + 5 < mylen) ? 1.f : 0.f;                                 \
            m6 = (i + 6 < mylen) ? 1.f : 0.f;                                 \
            m7 = (i + 7 < mylen) ? 1.f : 0.f;                                 \
            f32x4 q0, q1, q2, q3, q4, q5, q6, q7;                             \
            load8x16(TPTRX(0), TPTRX(1), TPTRX(2), TPTRX(3),                  \
                     TPTRX(4), TPTRX(5), TPTRX(6), TPTRX(7),                  \
                     q0, q1, q2, q3, q4, q5, q6, q7);                         \
            f32x4 u0, u1, u2, u3, u4, u5, u6, u7;                             \
            load8x16(tabA + __float_as_int(q0.w), tabA + __float_as_int(q1.w),\
                     tabA + __float_as_int(q2.w), tabA + __float_as_int(q3.w),\
                     tabA + __float_as_int(q4.w), tabA + __float_as_int(q5.w),\
                     tabA + __float_as_int(q6.w), tabA + __float_as_int(q7.w),\
                     u0, u1, u2, u3, u4, u5, u6, u7);                         \
            SAPX(0); SAPX(1); SAPX(2); SAPX(3);                               \
            SAPX(4); SAPX(5); SAPX(6); SAPX(7);                               \
        }                                                                     \
    } while (0)

#define TPTRX(K) ((const char*)epsv +                                         \
    (size_t)(s0 + ((i + K) < mylen ? (i + K) : mclamp)) * 16)
#define SAPX(K)                                                               \
    do { f32x4 uu = u##K; uu.x *= m##K; uu.y *= m##K; uu.z *= m##K;           \
         ACC16(q##K, uu); } while (0)

// ---------------------------------------------------------------------------
struct KP {
    const void* r_ij;
    const void *w_rad, *b_rad, *w_direct, *w1, *b1, *w2, *b2, *w3, *b3, *w_v, *w_d;
    const int* src;
    float* wcat; float* tabI; int* counts; int* rowstart; int* coarse;
    unsigned short* rank; void* epsv; void* out;
    int N, E, NB, nodeBlocks;
};

__device__ __forceinline__ float wload(const KP& P, int i, bool f32) {
    if (i < O_BRAD) return ldf(P.w_rad,    i - O_WRAD, f32);
    if (i < O_WDIR) return ldf(P.b_rad,    i - O_BRAD, f32);
    if (i < O_W1)   return ldf(P.w_direct, i - O_WDIR, f32);
    if (i < O_B1)   return ldf(P.w1,       i - O_W1,   f32);
    if (i < O_W2)   return ldf(P.b1,       i - O_B1,   f32);
    if (i < O_B2)   return ldf(P.w2,       i - O_W2,   f32);
    if (i < O_W3)   return ldf(P.b2,       i - O_B2,   f32);
    if (i < O_B3)   return ldf(P.w3,       i - O_W3,   f32);
    if (i < O_WV)   return ldf(P.b3,       i - O_B3,   f32);
    if (i < O_WD)   return ldf(P.w_v,      i - O_WV,   f32);
    return ldf(P.w_d, i - O_WD, f32);
}

template <bool P16>
__global__ void __launch_bounds__(256, 3) k_fused(KP P) {
    cg::grid_group grid = cg::this_grid();
    const int nb  = (int)gridDim.x;
    const int bid = (int)blockIdx.x;
    const int tid = (int)threadIdx.x;
    const int nthreads = nb * 256;
    const int gtid = bid * 256 + tid;
    const bool f32 = detect_f32(P.r_ij);

    __shared__ float Lh[EPB][32], Lt1[EPB][64], Lt2[EPB][64], Lrad[EPB][32];

    // ---- phase 1: wcat concat + zero counts ----
    for (int i = gtid; i < W_TOT; i += nthreads) P.wcat[i] = wload(P, i, f32);
    for (int i = gtid; i < P.N; i += nthreads) P.counts[i] = 0;
    grid.sync();

    // ---- phase 2: rank atomics + table build ----
    for (int e = gtid; e < P.E; e += nthreads)
        P.rank[e] = (unsigned short)atomicAdd(&P.counts[P.src[e]], 1);
    {
        const int s = tid >> 6;
        const int j = tid & 63;
        for (int v = bid; v < TSIZE / EPB; v += nb) {
            const int e = v * EPB + s;
            const float d = (float)e * (DMAX / (float)(TSIZE - 1));
            float enc[8];
#pragma unroll
            for (int k = 0; k < 8; k++) {
                float t = (d - (float)k * (1.0f / 7.0f)) * 8.0f;
                enc[k] = expf(-t * t);
            }
            if (j < 32) {
                float hv = P.wcat[O_BRAD + j];
#pragma unroll
                for (int k = 0; k < 8; k++)
                    hv = fmaf(enc[k], P.wcat[O_WRAD + k * 32 + j], hv);
                Lh[s][j] = hv;
            }
            __syncthreads();
            {
                float vv = P.wcat[O_B1 + j];
#pragma unroll
                for (int i = 0; i < 32; i++)
                    vv = fmaf(Lh[s][i], P.wcat[O_W1 + i * 64 + j], vv);
                Lt1[s][j] = lrelu(vv);
            }
            __syncthreads();
            {
                float vv = P.wcat[O_B2 + j];
#pragma unroll
                for (int i = 0; i < 64; i++)
                    vv = fmaf(Lt1[s][i], P.wcat[O_W2 + i * 64 + j], vv);
                Lt2[s][j] = lrelu(vv);
            }
            __syncthreads();
            if (j < 32) {
                float vv = P.wcat[O_B3 + j];
#pragma unroll
                for (int i = 0; i < 64; i++)
                    vv = fmaf(Lt2[s][i], P.wcat[O_W3 + i * 32 + j], vv);
#pragma unroll
                for (int i = 0; i < 32; i++)
                    vv = fmaf(Lh[s][i], P.wcat[O_WDIR + i * 32 + j], vv);
                Lrad[s][j] = vv;
            }
            __syncthreads();
            if (j < 32) {
                float sv = 0.0f, sd = 0.0f;
#pragma unroll
                for (int i = 0; i < 32; i++) {
                    float ri = Lrad[s][i];
                    sv = fmaf(ri, P.wcat[O_WV + i * 32 + j], sv);
                    sd = fmaf(ri, P.wcat[O_WD + i * 32 + j], sd);
                }
                float* row = P.tabI + (size_t)e * ROWF + j * 4;
                row[0] = Lrad[s][j];
                row[1] = sv;
                row[2] = sd;
                row[3] = 0.0f;
            }
            __syncthreads();
        }
    }
    grid.sync();

    // ---- phase 3a: coarse sums (wave per 64-node group) ----
    const int gw = gtid >> 6, ln = tid & 63, nw = nthreads >> 6;
    for (int b = gw; b < P.NB; b += nw) {
        const int n = b * 64 + ln;
        int s = (n < P.N) ? P.counts[n] : 0;
        for (int off = 32; off > 0; off >>= 1) s += __shfl_down(s, off);
        if (ln == 0) P.coarse[b] = s;
    }
    grid.sync();

    // ---- phase 3b: rowstart prefix ----
    for (int b = gw; b < P.NB; b += nw) {
        int cp = 0;
        for (int j = ln; j < b; j += 64) cp += P.coarse[j];
        for (int off = 32; off > 0; off >>= 1) cp += __shfl_down(cp, off);
        const int cpre = __shfl(cp, 0);
        const int n = b * 64 + ln;
        const int v = (n < P.N) ? P.counts[n] : 0;
        int inc = v;
        for (int off = 1; off < 64; off <<= 1) {
            int y = __shfl_up(inc, off);
            if (ln >= off) inc += y;
        }
        if (n < P.N) P.rowstart[n] = cpre + inc - v;
        if (n == P.N - 1) P.rowstart[P.N] = cpre + inc;
    }
    grid.sync();

    // ---- phase 4: payload place ----
    for (int e = gtid; e < P.E; e += nthreads) {
        const int pos = P.rowstart[P.src[e]] + (int)P.rank[e];
        const float x = ldf(P.r_ij, 3 * e + 0, f32);
        const float y = ldf(P.r_ij, 3 * e + 1, f32);
        const float z = ldf(P.r_ij, 3 * e + 2, f32);
        const float d2 = x * x + y * y + z * z;
        const float inv = rsqrtf(1.0f + 49.0f * d2);
        const float u = fminf(sqrtf(d2), DMAX) * ((float)(TSIZE - 1) / DMAX);
        const int ti = (int)(u + 0.5f);
        const float rs0 = 7.0f * x * inv, rs1 = 7.0f * y * inv,
                    rs2 = 7.0f * z * inv;
        if (P16) {
            ((float4*)P.epsv)[pos] =
                make_float4(rs0, rs1, rs2, __int_as_float(ti * ROWB));
        } else {
            const unsigned int h0 = __half_as_ushort(__float2half(rs0));
            const unsigned int h1 = __half_as_ushort(__float2half(rs1));
            const unsigned int h2 = __half_as_ushort(__float2half(rs2));
            ((uint2*)P.epsv)[pos] =
                make_uint2(h0 | (h1 << 16), h2 | ((unsigned)ti << 16));
        }
    }
    grid.sync();

    // ---- phase 5: per-node accumulation (R25 asm pipeline) ----
    {
        const void* epsv = P.epsv;
        const int wave = tid >> 6;
        const int lane = tid & 63;
        const int a = lane & 31;
        const int half = lane >> 5;
        const char* tabA = (const char*)P.tabI + a * 16;
        const int N = P.N;
        for (int vb = bid; vb < P.nodeBlocks; vb += nb) {
            const int n0 = (vb * NPB + wave) * 2;
            const int myn = n0 + half;
            int s0 = 0, s1 = 0;
            if (myn < N) { s0 = P.rowstart[myn]; s1 = P.rowstart[myn + 1]; }
            const int mylen = s1 - s0;
            const int lenA = __shfl(mylen, 0);
            const int lenB = __shfl(mylen, 32);
            const int minl = min(lenA, lenB);
            const int maxl = max(lenA, lenB);
            const int mclamp = max(mylen - 1, 0);

            float accA = 0.f, v0 = 0.f, v1 = 0.f, v2 = 0.f;
            float d00 = 0.f, d01 = 0.f, d02 = 0.f,
                  d10 = 0.f, d11 = 0.f, d12 = 0.f,
                  d20 = 0.f, d21 = 0.f, d22 = 0.f;

            if (P16) {
                NODES_BODY_P16();
            } else {
                for (int i = 0; i < maxl; i++) {
                    if (i < mylen) {
                        const u32x2 qh = *((const u32x2*)epsv + (s0 + i));
                        const float x = __half2float(__ushort_as_half(
                            (unsigned short)(qh.x & 0xffffu)));
                        const float y = __half2float(__ushort_as_half(
                            (unsigned short)(qh.x >> 16)));
                        const float z = __half2float(__ushort_as_half(
                            (unsigned short)(qh.y & 0xffffu)));
                        const TE t = *(const TE*)(tabA + (int)(qh.y >> 16) * ROWB);
                        accA += t.r;
                        v0 += t.v * x; v1 += t.v * y; v2 += t.v * z;
                        const float _tx = t.d * x, _ty = t.d * y, _tz = t.d * z;
                        d00 += _tx * x; d01 += _tx * y; d02 += _tx * z;
                        d10 += _ty * x; d11 += _ty * y; d12 += _ty * z;
                        d20 += _tz * x; d21 += _tz * y; d22 += _tz * z;
                    }
                }
            }

            if (myn < N) {
                const size_t baseV = (size_t)N * 32;
                const size_t baseD = (size_t)N * 128;
                stf(P.out, (size_t)myn * 32 + a, accA, f32);
                const size_t vb2 = baseV + (size_t)myn * 96 + a * 3;
                stf(P.out, vb2 + 0, v0, f32);
                stf(P.out, vb2 + 1, v1, f32);
                stf(P.out, vb2 + 2, v2, f32);
                const size_t db = baseD + (size_t)myn * 288 + a * 9;
                stf(P.out, db + 0, d00, f32);
                stf(P.out, db + 1, d01, f32);
                stf(P.out, db + 2, d02, f32);
                stf(P.out, db + 3, d10, f32);
                stf(P.out, db + 4, d11, f32);
                stf(P.out, db + 5, d12, f32);
                stf(P.out, db + 6, d20, f32);
                stf(P.out, db + 7, d21, f32);
                stf(P.out, db + 8, d22, f32);
            }
        }
    }
}

// ======================= R26 fallback chain (proven) ========================
__global__ void __launch_bounds__(256) k_prep(
    const void* __restrict__ r_ij,
    const void* w_rad, const void* b_rad, const void* w_direct,
    const void* w1, const void* b1, const void* w2, const void* b2,
    const void* w3, const void* b3, const void* w_v, const void* w_d,
    float* __restrict__ wcat, int* __restrict__ flag,
    int* __restrict__ counts, int N) {
    const int b = blockIdx.x;
    if (b == 0) {
        if (threadIdx.x == 0) flag[0] = detect_f32(r_ij) ? 1 : 0;
    } else if (b <= 11) {
        const bool f32 = detect_f32(r_ij);
        const void* src; int cnt; int off;
        switch (b) {
            case 1:  src = w_rad;    cnt = 256;  off = O_WRAD; break;
            case 2:  src = b_rad;    cnt = 32;   off = O_BRAD; break;
            case 3:  src = w_direct; cnt = 1024; off = O_WDIR; break;
            case 4:  src = w1;       cnt = 2048; off = O_W1;   break;
            case 5:  src = b1;       cnt = 64;   off = O_B1;   break;
            case 6:  src = w2;       cnt = 4096; off = O_W2;   break;
            case 7:  src = b2;       cnt = 64;   off = O_B2;   break;
            case 8:  src = w3;       cnt = 2048; off = O_W3;   break;
            case 9:  src = b3;       cnt = 32;   off = O_B3;   break;
            case 10: src = w_v;      cnt = 1024; off = O_WV;   break;
            default: src = w_d;      cnt = 1024; off = O_WD;   break;
        }
        for (int i = threadIdx.x; i < cnt; i += 256)
            wcat[off + i] = ldf(src, i, f32);
    } else {
        const int i = (b - 12) * 256 + threadIdx.x;
        if (i < N) counts[i] = 0;
    }
}

__global__ void __launch_bounds__(64 * EPB) k_tabrank(
    const float* __restrict__ wcat, float* __restrict__ tabI,
    const int* __restrict__ src, int* __restrict__ counts,
    unsigned short* __restrict__ rank, int E) {
    __shared__ float Lh[EPB][32], Lt1[EPB][64], Lt2[EPB][64], Lrad[EPB][32];
    const int TB = TSIZE / EPB;
    if (blockIdx.x >= TB) {
        const int e = (blockIdx.x - TB) * 256 + threadIdx.x;
        if (e < E) rank[e] = (unsigned short)atomicAdd(&counts[src[e]], 1);
        return;
    }
    const int s = threadIdx.x >> 6;
    const int j = threadIdx.x & 63;
    const int e = blockIdx.x * EPB + s;
    const float d = (float)e * (DMAX / (float)(TSIZE - 1));
    float enc[8];
#pragma unroll
    for (int k = 0; k < 8; k++) {
        float t = (d - (float)k * (1.0f / 7.0f)) * 8.0f;
        enc[k] = expf(-t * t);
    }
    if (j < 32) {
        float hv = wcat[O_BRAD + j];
#pragma unroll
        for (int k = 0; k < 8; k++) hv = fmaf(enc[k], wcat[O_WRAD + k * 32 + j], hv);
        Lh[s][j] = hv;
    }
    __syncthreads();
    {
        float v = wcat[O_B1 + j];
#pragma unroll
        for (int i = 0; i < 32; i++) v = fmaf(Lh[s][i], wcat[O_W1 + i * 64 + j], v);
        Lt1[s][j] = lrelu(v);
    }
    __syncthreads();
    {
        float v = wcat[O_B2 + j];
#pragma unroll
        for (int i = 0; i < 64; i++) v = fmaf(Lt1[s][i], wcat[O_W2 + i * 64 + j], v);
        Lt2[s][j] = lrelu(v);
    }
    __syncthreads();
    if (j < 32) {
        float v = wcat[O_B3 + j];
#pragma unroll
        for (int i = 0; i < 64; i++) v = fmaf(Lt2[s][i], wcat[O_W3 + i * 32 + j], v);
#pragma unroll
        for (int i = 0; i < 32; i++) v = fmaf(Lh[s][i], wcat[O_WDIR + i * 32 + j], v);
        Lrad[s][j] = v;
    }
    __syncthreads();
    if (j < 32) {
        float sv = 0.0f, sd = 0.0f;
#pragma unroll
        for (int i = 0; i < 32; i++) {
            float ri = Lrad[s][i];
            sv = fmaf(ri, wcat[O_WV + i * 32 + j], sv);
            sd = fmaf(ri, wcat[O_WD + i * 32 + j], sd);
        }
        float* row = tabI + (size_t)e * ROWF + j * 4;
        row[0] = Lrad[s][j];
        row[1] = sv;
        row[2] = sd;
        row[3] = 0.0f;
    }
}

__global__ void __launch_bounds__(64) k_sum(const int* __restrict__ counts,
                                            int* __restrict__ coarse, int N) {
    const int lane = threadIdx.x;
    const int n = blockIdx.x * 64 + lane;
    int s = (n < N) ? counts[n] : 0;
    for (int off = 32; off > 0; off >>= 1) s += __shfl_down(s, off);
    if (lane == 0) coarse[blockIdx.x] = s;
}

__global__ void __launch_bounds__(64) k_scan2c(const int* __restrict__ counts,
                                               const int* __restrict__ coarse,
                                               int* __restrict__ rowstart, int N) {
    const int lane = threadIdx.x;
    const int b = blockIdx.x;
    int cp = 0;
    for (int j = lane; j < b; j += 64) cp += coarse[j];
    for (int off = 32; off > 0; off >>= 1) cp += __shfl_down(cp, off);
    const int cpre = __shfl(cp, 0);
    const int n = b * 64 + lane;
    const int v = (n < N) ? counts[n] : 0;
    int inc = v;
    for (int off = 1; off < 64; off <<= 1) {
        int y = __shfl_up(inc, off);
        if (lane >= off) inc += y;
    }
    if (n < N) rowstart[n] = cpre + inc - v;
    if (n == N - 1) rowstart[N] = cpre + inc;
}

template <bool P16>
__global__ void __launch_bounds__(256) k_place2(
        const int* __restrict__ src, const unsigned short* __restrict__ rank,
        const int* __restrict__ rowstart, const void* __restrict__ r_ij,
        const int* __restrict__ flag, void* __restrict__ epsv, int E) {
    const bool f32 = flag[0] != 0;
    const int e = blockIdx.x * 256 + threadIdx.x;
    if (e >= E) return;
    const int pos = rowstart[src[e]] + (int)rank[e];
    const float x = ldf(r_ij, 3 * e + 0, f32);
    const float y = ldf(r_ij, 3 * e + 1, f32);
    const float z = ldf(r_ij, 3 * e + 2, f32);
    const float d2 = x * x + y * y + z * z;
    const float inv = rsqrtf(1.0f + 49.0f * d2);
    const float u = fminf(sqrtf(d2), DMAX) * ((float)(TSIZE - 1) / DMAX);
    const int ti = (int)(u + 0.5f);
    const float rs0 = 7.0f * x * inv, rs1 = 7.0f * y * inv, rs2 = 7.0f * z * inv;
    if (P16) {
        ((float4*)epsv)[pos] =
            make_float4(rs0, rs1, rs2, __int_as_float(ti * ROWB));
    } else {
        const unsigned int h0 = __half_as_ushort(__float2half(rs0));
        const unsigned int h1 = __half_as_ushort(__float2half(rs1));
        const unsigned int h2 = __half_as_ushort(__float2half(rs2));
        ((uint2*)epsv)[pos] =
            make_uint2(h0 | (h1 << 16), h2 | ((unsigned)ti << 16));
    }
}

template <bool P16>
__global__ void __launch_bounds__(64 * NPB, 3) k_nodes2(
    const void* __restrict__ epsv,
    const int* __restrict__ rowstart,
    const float* __restrict__ tabI,
    const int* __restrict__ flag,
    void* __restrict__ out, int N) {
    const int wave = threadIdx.x >> 6;
    const int lane = threadIdx.x & 63;
    const int n0 = (blockIdx.x * NPB + wave) * 2;
    const int a = lane & 31;
    const int half = lane >> 5;
    const int myn = n0 + half;
    const bool f32 = flag[0] != 0;
    const char* tabA = (const char*)tabI + a * 16;

    int s0 = 0, s1 = 0;
    if (myn < N) { s0 = rowstart[myn]; s1 = rowstart[myn + 1]; }
    const int mylen = s1 - s0;
    const int lenA = __shfl(mylen, 0);
    const int lenB = __shfl(mylen, 32);
    const int minl = min(lenA, lenB);
    const int maxl = max(lenA, lenB);
    const int mclamp = max(mylen - 1, 0);

    float accA = 0.f, v0 = 0.f, v1 = 0.f, v2 = 0.f;
    float d00 = 0.f, d01 = 0.f, d02 = 0.f,
          d10 = 0.f, d11 = 0.f, d12 = 0.f,
          d20 = 0.f, d21 = 0.f, d22 = 0.f;

    if (P16) {
        NODES_BODY_P16();
    } else {
        for (int i = 0; i < maxl; i++) {
            if (i < mylen) {
                const u32x2 qh = *((const u32x2*)epsv + (s0 + i));
                const float x = __half2float(__ushort_as_half(
                    (unsigned short)(qh.x & 0xffffu)));
                const float y = __half2float(__ushort_as_half(
                    (unsigned short)(qh.x >> 16)));
                const float z = __half2float(__ushort_as_half(
                    (unsigned short)(qh.y & 0xffffu)));
                const TE t = *(const TE*)(tabA + (int)(qh.y >> 16) * ROWB);
                accA += t.r;
                v0 += t.v * x; v1 += t.v * y; v2 += t.v * z;
                const float _tx = t.d * x, _ty = t.d * y, _tz = t.d * z;
                d00 += _tx * x; d01 += _tx * y; d02 += _tx * z;
                d10 += _ty * x; d11 += _ty * y; d12 += _ty * z;
                d20 += _tz * x; d21 += _tz * y; d22 += _tz * z;
            }
        }
    }

    if (myn >= N) return;
    const size_t baseV = (size_t)N * 32;
    const size_t baseD = (size_t)N * 128;
    stf(out, (size_t)myn * 32 + a, accA, f32);
    const size_t vb = baseV + (size_t)myn * 96 + a * 3;
    stf(out, vb + 0, v0, f32);
    stf(out, vb + 1, v1, f32);
    stf(out, vb + 2, v2, f32);
    const size_t db = baseD + (size_t)myn * 288 + a * 9;
    stf(out, db + 0, d00, f32);
    stf(out, db + 1, d01, f32);
    stf(out, db + 2, d02, f32);
    stf(out, db + 3, d10, f32);
    stf(out, db + 4, d11, f32);
    stf(out, db + 5, d12, f32);
    stf(out, db + 6, d20, f32);
    stf(out, db + 7, d21, f32);
    stf(out, db + 8, d22, f32);
}

// --- fallback (ws too small for payload): perm + on-the-fly recompute ------
__global__ void __launch_bounds__(256) k_place_g(
        const int* __restrict__ src, const unsigned short* __restrict__ rank,
        const int* __restrict__ rowstart, int* __restrict__ perm, int E) {
    const int e = blockIdx.x * 256 + threadIdx.x;
    if (e < E) perm[rowstart[src[e]] + (int)rank[e]] = e;
}
__global__ void __launch_bounds__(256) k_nodes_fb(
    const int* __restrict__ perm, const void* __restrict__ r_ij,
    const int* __restrict__ rowstart, const float* __restrict__ tabI,
    const int* __restrict__ flag, void* __restrict__ out, int N) {
    const int wave = threadIdx.x >> 6;
    const int lane = threadIdx.x & 63;
    const int n = blockIdx.x * 4 + wave;
    if (n >= N) return;
    const int a = lane & 31;
    const bool hi = (lane >> 5) != 0;
    const bool f32 = flag[0] != 0;
    const int s0 = rowstart[n], s1 = rowstart[n + 1];
    float accR = 0.f, acc1 = 0.f, acc2 = 0.f, acc3 = 0.f,
          acc4 = 0.f, acc5 = 0.f, acc6 = 0.f;
    for (int idx = s0; idx < s1; idx++) {
        const int e = perm[idx];
        const float x0 = ldf(r_ij, 3 * e + 0, f32);
        const float y0 = ldf(r_ij, 3 * e + 1, f32);
        const float z0 = ldf(r_ij, 3 * e + 2, f32);
        const float d2 = x0 * x0 + y0 * y0 + z0 * z0;
        const float inv = rsqrtf(1.0f + 49.0f * d2);
        const float x = 7.0f * x0 * inv, y = 7.0f * y0 * inv, z = 7.0f * z0 * inv;
        const float u = fminf(sqrtf(d2), DMAX) * ((float)(TSIZE - 1) / DMAX);
        const int b = (int)(u + 0.5f) * ROWF + a * 4;
        const float ra = tabI[b], rv = tabI[b + 1], rd = tabI[b + 2];
        const float b1 = (hi ? rd : rv) * (hi ? y : 1.0f);
        const float b2 = rd * (hi ? z : x);
        accR += ra;
        acc1 += b1 * x; acc2 += b1 * y; acc3 += b1 * z;
        acc4 += b2 * x; acc5 += b2 * y; acc6 += b2 * z;
    }
    const size_t baseV = (size_t)N * 32;
    const size_t baseD = (size_t)N * 128;
    if (!hi) {
        stf(out, (size_t)n * 32 + a, accR, f32);
        const size_t vb = baseV + (size_t)n * 96 + a * 3;
        stf(out, vb + 0, acc1, f32);
        stf(out, vb + 1, acc2, f32);
        stf(out, vb + 2, acc3, f32);
        const size_t db = baseD + (size_t)n * 288 + a * 9;
        stf(out, db + 0, acc4, f32);
        stf(out, db + 1, acc5, f32);
        stf(out, db + 2, acc6, f32);
    } else {
        const size_t db = baseD + (size_t)n * 288 + a * 9;
        stf(out, db + 3, acc1, f32);
        stf(out, db + 4, acc2, f32);
        stf(out, db + 5, acc3, f32);
        stf(out, db + 6, acc4, f32);
        stf(out, db + 7, acc5, f32);
        stf(out, db + 8, acc6, f32);
    }
}

extern "C" void kernel_launch(void* const* d_in, const int* in_sizes, int n_in,
                              void* d_out, int out_size, void* d_ws, size_t ws_size,
                              hipStream_t stream) {
    const void* r_ij     = d_in[0];
    const void* w_rad    = d_in[1];
    const void* b_rad    = d_in[2];
    const void* w_direct = d_in[3];
    const void* w1       = d_in[4];
    const void* b1       = d_in[5];
    const void* w2       = d_in[6];
    const void* b2       = d_in[7];
    const void* w3       = d_in[8];
    const void* b3       = d_in[9];
    const void* w_v      = d_in[10];
    const void* w_d      = d_in[11];
    const int* edges_src = (const int*)d_in[12];

    const int E = in_sizes[12];
    const int N = out_size / 416;
    const int TB = TSIZE / EPB;
    const int ZB = (N + 255) / 256;
    const int EB = (E + 255) / 256;
    const int NB = (N + 63) / 64;
    const int nodeBlocks = (N + 2 * NPB - 1) / (2 * NPB);

    const size_t tailBytes = ((size_t)W_TOT + 4) * 4 + (size_t)TSIZE * ROWF * 4
                           + ((size_t)N + N + 1 + NB) * 4 + (size_t)E * 2 + 64;
    const bool p16 = ws_size >= (size_t)E * 16 + tailBytes;
    const bool p8  = !p16 && ws_size >= (size_t)E * 8 + tailBytes;

    char* w = (char*)d_ws;
    if (p16 || p8) {
        const size_t slot = (size_t)E * (p16 ? 16 : 8);
        void* eps      = (void*)w;
        float* wcat    = (float*)(w + slot);
        int* flag      = (int*)(wcat + W_TOT);
        float* tabI    = (float*)(flag + 4);
        int* counts    = (int*)(tabI + (size_t)TSIZE * ROWF);
        int* rowstart  = counts + N;
        int* coarse    = rowstart + N + 1;
        unsigned short* rank = (unsigned short*)(coarse + NB);

        // ---- try single cooperative kernel ----
        static int s_grid = 0;
        if (s_grid == 0) {
            int perCU = 0;
            if (hipOccupancyMaxActiveBlocksPerMultiprocessor(
                    &perCU, k_fused<true>, 256, 0) != hipSuccess || perCU <= 0)
                perCU = 2;
            s_grid = perCU * 256;          // 256 CUs on MI355X
        }
        KP hp;
        hp.r_ij = r_ij;
        hp.w_rad = w_rad; hp.b_rad = b_rad; hp.w_direct = w_direct;
        hp.w1 = w1; hp.b1 = b1; hp.w2 = w2; hp.b2 = b2;
        hp.w3 = w3; hp.b3 = b3; hp.w_v = w_v; hp.w_d = w_d;
        hp.src = edges_src;
        hp.wcat = wcat; hp.tabI = tabI; hp.counts = counts;
        hp.rowstart = rowstart; hp.coarse = coarse; hp.rank = rank;
        hp.epsv = eps; hp.out = d_out;
        hp.N = N; hp.E = E; hp.NB = NB; hp.nodeBlocks = nodeBlocks;
        void* kargs[] = { (void*)&hp };
        hipError_t cerr = hipLaunchCooperativeKernel(
            p16 ? reinterpret_cast<const void*>(&k_fused<true>)
                : reinterpret_cast<const void*>(&k_fused<false>),
            dim3(s_grid), dim3(256), kargs, 0, stream);
        if (cerr == hipSuccess) return;

        // ---- fallback: proven R26 6-kernel chain ----
        k_prep<<<12 + ZB, 256, 0, stream>>>(
            r_ij, w_rad, b_rad, w_direct, w1, b1, w2, b2, w3, b3, w_v, w_d,
            wcat, flag, counts, N);
        k_tabrank<<<TB + EB, 64 * EPB, 0, stream>>>(
            wcat, tabI, edges_src, counts, rank, E);
        k_sum<<<NB, 64, 0, stream>>>(counts, coarse, N);
        k_scan2c<<<NB, 64, 0, stream>>>(counts, coarse, rowstart, N);
        if (p16) {
            k_place2<true><<<EB, 256, 0, stream>>>(
                edges_src, rank, rowstart, r_ij, flag, eps, E);
            k_nodes2<true><<<nodeBlocks, 64 * NPB, 0, stream>>>(
                eps, rowstart, tabI, flag, d_out, N);
        } else {
            k_place2<false><<<EB, 256, 0, stream>>>(
                edges_src, rank, rowstart, r_ij, flag, eps, E);
            k_nodes2<false><<<nodeBlocks, 64 * NPB, 0, stream>>>(
                eps, rowstart, tabI, flag, d_out, N);
        }
    } else {
        // minimal-workspace fallback: perm-indexed nodes
        int* perm      = (int*)w;
        float* wcat    = (float*)(w + (size_t)E * 4);
        int* flag      = (int*)(wcat + W_TOT);
        float* tabI    = (float*)(flag + 4);
        int* counts    = (int*)(tabI + (size_t)TSIZE * ROWF);
        int* rowstart  = counts + N;
        int* coarse    = rowstart + N + 1;
        unsigned short* rank = (unsigned short*)(coarse + NB);

        k_prep<<<12 + ZB, 256, 0, stream>>>(
            r_ij, w_rad, b_rad, w_direct, w1, b1, w2, b2, w3, b3, w_v, w_d,
            wcat, flag, counts, N);
        k_tabrank<<<TB + EB, 64 * EPB, 0, stream>>>(
            wcat, tabI, edges_src, counts, rank, E);
        k_sum<<<NB, 64, 0, stream>>>(counts, coarse, N);
        k_scan2c<<<NB, 64, 0, stream>>>(counts, coarse, rowstart, N);
        k_place_g<<<EB, 256, 0, stream>>>(edges_src, rank, rowstart, perm, E);
        k_nodes_fb<<<(N + 3) / 4, 256, 0, stream>>>(
            perm, r_ij, rowstart, tabI, flag, d_out, N);
    }
}